// Round 12
// baseline (358.691 us; speedup 1.0000x reference)
//
#include <hip/hip_runtime.h>
#include <hip/hip_bf16.h>
#include <math.h>

// ---------------------------------------------------------------------------
// torso_left_right_actor: x@W0+b0 -> GraphConv -> tanh -> GraphConv -> tanh
//   -> @W3+b3 -> tanh -> global_mean_pool -> NormalParamExtractor
// R12 = R11 resubmit (broker timeout, no measurement):
//     fused k_gconv = gather(->LDS tile) + MFMA conv (+ fused h3 in layer 2).
//     agg and h2 never touch global memory. Weights transposed-staged in LDS
//     as bf16 (72-pitch rows -> 2-way bank aliasing = free).
//     Frag layouts (HW-verified R10): A row=lane&15,k=8*(lane>>4)+i;
//     B col=lane&15 same k; C/D col=lane&15,row=(lane>>4)*4+reg.
// ---------------------------------------------------------------------------

#define CAP 64
#define FILL_PARTS 8
#define FILL_BPP 1024
typedef __hip_bfloat16 bf16;
typedef __attribute__((ext_vector_type(8))) short bf16x8;
typedef __attribute__((ext_vector_type(4))) float f32x4;

// h = bf16(x @ W0 + b0)   (x: [N,11], W0: [11,64])
__global__ __launch_bounds__(256) void k_in(const float* __restrict__ x,
    const float* __restrict__ W0, const float* __restrict__ b0,
    bf16* __restrict__ h, int N) {
  __shared__ float w[11 * 64];
  __shared__ float xl[4][12];
  int tid = threadIdx.x;
  for (int i = tid; i < 11 * 64; i += 256) w[i] = W0[i];
  int row0 = blockIdx.x * 4;
  if (tid < 44) {
    int r = tid / 11, k = tid % 11;
    int g = row0 + r;
    xl[r][k] = (g < N) ? x[(size_t)g * 11 + k] : 0.f;
  }
  __syncthreads();
  int c = tid & 63, r = tid >> 6;
  int g = row0 + r;
  float acc = b0[c];
#pragma unroll
  for (int k = 0; k < 11; ++k) acc += xl[r][k] * w[k * 64 + c];
  if (g < N) h[(size_t)g * 64 + c] = __float2bfloat16(acc);
}

// CSR build, dst-range binned (8 partitions -> XCD-L2-local RMW).
// cnt must be pre-zeroed.
__global__ __launch_bounds__(256) void k_fill(const int* __restrict__ ei,
    int* __restrict__ cnt, int* __restrict__ csr, int E, int N) {
  int p  = blockIdx.x & 7;
  int sb = blockIdx.x >> 3;
  int nb = gridDim.x >> 3;
  int part = (N + 7) >> 3;
  int lo = p * part, hi = min(N, lo + part);
  const int* src = ei;
  const int* dst = ei + E;
  int E4 = E >> 2;
  const int4* d4 = (const int4*)dst;
  for (int i = sb * 256 + threadIdx.x; i < E4; i += nb * 256) {
    int4 dv = d4[i];
#pragma unroll
    for (int k = 0; k < 4; ++k) {
      int d = (&dv.x)[k];
      if (d >= lo && d < hi) {
        int s = src[i * 4 + k];
        int pos = atomicAdd(&cnt[d], 1);
        if (pos < CAP) csr[(size_t)d * CAP + pos] = s;
      }
    }
  }
  if (sb == 0 && threadIdx.x < (E & 3)) {   // tail edges
    int e = (E4 << 2) + threadIdx.x;
    int d = dst[e];
    if (d >= lo && d < hi) {
      int s = src[e];
      int pos = atomicAdd(&cnt[d], 1);
      if (pos < CAP) csr[(size_t)d * CAP + pos] = s;
    }
  }
}

// Fused: gather 64 nodes into LDS tile + conv via MFMA.
// DO_H3=0: out = bf16(tanh(agg@Wrel + brel + hin@Wroot)) -> hout [N,64]
// DO_H3=1: additionally h3out = tanh(h2@W3 + b3) [N,16]; h2 stays in LDS.
template <int DO_H3>
__global__ __launch_bounds__(256) void k_gconv(
    const bf16* __restrict__ hin, const int* __restrict__ csr,
    const int* __restrict__ cnt, const float* __restrict__ Wrel,
    const float* __restrict__ brel, const float* __restrict__ Wroot,
    const float* __restrict__ W3, const float* __restrict__ b3,
    bf16* __restrict__ hout, float* __restrict__ h3out, int N) {
  __shared__ bf16 wT[2][64][72];    // transposed weights: wT[m][col][k]
  __shared__ bf16 tile[4][16][72];  // per-wave agg (then h2) tile
  int tid = threadIdx.x;
  // Stage W^T as bf16 (coalesced global read; LDS-write conflicts once/block).
  for (int j = tid; j < 4096; j += 256) {
    int k = j >> 6, col = j & 63;
    wT[0][col][k] = __float2bfloat16(Wrel[j]);
    wT[1][col][k] = __float2bfloat16(Wroot[j]);
  }
  int lane = tid & 63;
  int wv = __builtin_amdgcn_readfirstlane(tid >> 6);
  int rb = blockIdx.x * 64;
  // ---- gather phase: wave wv gathers nodes rb+wv*16 .. +15 into its tile
  for (int t = 0; t < 16; ++t) {
    int n = rb + wv * 16 + t;
    float a0 = 0.f, a1 = 0.f, a2 = 0.f, a3 = 0.f;
    if (n < N) {
      int deg = min(cnt[n], CAP);               // wave-uniform
      int myidx = csr[(size_t)n * CAP + lane];  // coalesced 256B row
      int j = 0;
      for (; j + 4 <= deg; j += 4) {
        int s0 = __shfl(myidx, j + 0);
        int s1 = __shfl(myidx, j + 1);
        int s2 = __shfl(myidx, j + 2);
        int s3 = __shfl(myidx, j + 3);
        a0 += __bfloat162float(hin[(size_t)s0 * 64 + lane]);
        a1 += __bfloat162float(hin[(size_t)s1 * 64 + lane]);
        a2 += __bfloat162float(hin[(size_t)s2 * 64 + lane]);
        a3 += __bfloat162float(hin[(size_t)s3 * 64 + lane]);
      }
      for (; j < deg; ++j)
        a0 += __bfloat162float(hin[(size_t)__shfl(myidx, j) * 64 + lane]);
    }
    tile[wv][t][lane] = __float2bfloat16((a0 + a1) + (a2 + a3));
  }
  __syncthreads();  // wT visible to all waves (tile is per-wave anyway)
  // ---- conv phase
  int lr = lane & 15, lk = lane >> 4;
  bf16x8 a0 = *(const bf16x8*)&tile[wv][lr][lk * 8];
  bf16x8 a1 = *(const bf16x8*)&tile[wv][lr][lk * 8 + 32];
  int hrow = min(rb + wv * 16 + lr, N - 1);
  const bf16x8* Hp = (const bf16x8*)(hin + (size_t)hrow * 64 + lk * 8);
  bf16x8 h0 = Hp[0], h1 = Hp[4];
  f32x4 acc[4];
#pragma unroll
  for (int cb = 0; cb < 4; ++cb) {
    bf16x8 br0 = *(const bf16x8*)&wT[0][cb * 16 + lr][lk * 8];
    bf16x8 br1 = *(const bf16x8*)&wT[0][cb * 16 + lr][lk * 8 + 32];
    bf16x8 bo0 = *(const bf16x8*)&wT[1][cb * 16 + lr][lk * 8];
    bf16x8 bo1 = *(const bf16x8*)&wT[1][cb * 16 + lr][lk * 8 + 32];
    float bb = brel[cb * 16 + lr];
    f32x4 c0 = {bb, bb, bb, bb};
    c0 = __builtin_amdgcn_mfma_f32_16x16x32_bf16(a0, br0, c0, 0, 0, 0);
    c0 = __builtin_amdgcn_mfma_f32_16x16x32_bf16(a1, br1, c0, 0, 0, 0);
    c0 = __builtin_amdgcn_mfma_f32_16x16x32_bf16(h0, bo0, c0, 0, 0, 0);
    c0 = __builtin_amdgcn_mfma_f32_16x16x32_bf16(h1, bo1, c0, 0, 0, 0);
    acc[cb] = c0;
  }
  if (!DO_H3) {
#pragma unroll
    for (int cb = 0; cb < 4; ++cb)
#pragma unroll
      for (int r = 0; r < 4; ++r) {
        int row = rb + wv * 16 + lk * 4 + r;
        if (row < N)
          hout[(size_t)row * 64 + cb * 16 + lr] = __float2bfloat16(tanhf(acc[cb][r]));
      }
  } else {
    // h2 tile (tanh, bf16) back into LDS; then h3 = tanh(h2 @ W3 + b3).
#pragma unroll
    for (int cb = 0; cb < 4; ++cb)
#pragma unroll
      for (int r = 0; r < 4; ++r)
        tile[wv][lk * 4 + r][cb * 16 + lr] = __float2bfloat16(tanhf(acc[cb][r]));
    __syncthreads();  // ordering insurance (writes/reads are same-wave)
    bf16x8 p0 = *(const bf16x8*)&tile[wv][lr][lk * 8];
    bf16x8 p1 = *(const bf16x8*)&tile[wv][lr][lk * 8 + 32];
    bf16x8 q0, q1;
    bf16* q0p = (bf16*)&q0;
    bf16* q1p = (bf16*)&q1;
#pragma unroll
    for (int i = 0; i < 8; ++i) {  // W3 [64,16], L2-hot 4KB
      q0p[i] = __float2bfloat16(W3[(lk * 8 + i) * 16 + lr]);
      q1p[i] = __float2bfloat16(W3[(lk * 8 + i + 32) * 16 + lr]);
    }
    float b3v = b3[lr];
    f32x4 c3 = {b3v, b3v, b3v, b3v};
    c3 = __builtin_amdgcn_mfma_f32_16x16x32_bf16(p0, q0, c3, 0, 0, 0);
    c3 = __builtin_amdgcn_mfma_f32_16x16x32_bf16(p1, q1, c3, 0, 0, 0);
#pragma unroll
    for (int r = 0; r < 4; ++r) {
      int row = rb + wv * 16 + lk * 4 + r;
      if (row < N) h3out[(size_t)row * 16 + lr] = tanhf(c3[r]);
    }
  }
}

// Per-graph mean pool + NormalParamExtractor. batch is sorted.
__global__ __launch_bounds__(256) void k_pool(const float* __restrict__ h3,
    const int* __restrict__ batch, float* __restrict__ out, int N, int B) {
  __shared__ int srange[2];
  __shared__ float red[256];
  int b = blockIdx.x;
  int tid = threadIdx.x;
  if (tid < 2) {
    int target = b + tid;
    int lo = 0, hi = N;
    while (lo < hi) {
      int mid = (lo + hi) >> 1;
      if (batch[mid] < target) lo = mid + 1; else hi = mid;
    }
    srange[tid] = lo;
  }
  __syncthreads();
  int s = srange[0], e = srange[1];
  int f = tid & 15, g = tid >> 4;
  float acc = 0.f;
  for (int n = s + g; n < e; n += 16) acc += h3[(size_t)n * 16 + f];
  red[tid] = acc;
  __syncthreads();
  for (int stride = 128; stride >= 16; stride >>= 1) {
    if (tid < stride) red[tid] += red[tid + stride];
    __syncthreads();
  }
  if (tid < 16) {
    float cnt = (float)(e - s);
    float pooled = red[tid] / fmaxf(cnt, 1.0f);
    if (tid < 8) {
      out[(size_t)b * 8 + tid] = pooled;
    } else {
      float xx = pooled + 0.54132485461292f;  // log(expm1(1.0))
      float sp = (xx > 20.f) ? xx : log1pf(expf(xx));
      out[(size_t)B * 8 + (size_t)b * 8 + (tid - 8)] = fmaxf(sp, 1e-4f);
    }
  }
}

extern "C" void kernel_launch(void* const* d_in, const int* in_sizes, int n_in,
                              void* d_out, int out_size, void* d_ws, size_t ws_size,
                              hipStream_t stream) {
  const float* x      = (const float*)d_in[0];
  const int*   ei     = (const int*)d_in[1];
  const int*   batch  = (const int*)d_in[2];
  const float* W0     = (const float*)d_in[3];
  const float* b0     = (const float*)d_in[4];
  const float* Wrel1  = (const float*)d_in[5];
  const float* brel1  = (const float*)d_in[6];
  const float* Wroot1 = (const float*)d_in[7];
  const float* Wrel2  = (const float*)d_in[8];
  const float* brel2  = (const float*)d_in[9];
  const float* Wroot2 = (const float*)d_in[10];
  const float* W3     = (const float*)d_in[11];
  const float* b3     = (const float*)d_in[12];
  float* out = (float*)d_out;

  int N = in_sizes[0] / 11;
  int E = in_sizes[1] / 2;
  int B = out_size / 16;

  bf16*  hb   = (bf16*)d_ws;                      // [N,64] bf16 (h0)
  bf16*  h1b  = hb + (size_t)N * 64;              // [N,64] bf16 (h1)
  float* h3b  = (float*)(h1b + (size_t)N * 64);   // [N,16] f32
  int*   cnt  = (int*)(h3b + (size_t)N * 16);     // [N]
  int*   csr  = cnt + N;                          // [N,CAP]

  int nst = (N + 63) / 64;

  hipMemsetAsync(cnt, 0, (size_t)N * sizeof(int), stream);
  k_in<<<(N + 3) / 4, 256, 0, stream>>>(x, W0, b0, hb, N);
  k_fill<<<FILL_PARTS * FILL_BPP, 256, 0, stream>>>(ei, cnt, csr, E, N);

  // layer 1: gather(hb) + conv1 -> h1b
  k_gconv<0><<<nst, 256, 0, stream>>>(hb, csr, cnt, Wrel1, brel1, Wroot1,
                                      nullptr, nullptr, h1b, nullptr, N);
  // layer 2: gather(h1b) + conv2 + h3 -> h3b   (h2 never leaves LDS)
  k_gconv<1><<<nst, 256, 0, stream>>>(h1b, csr, cnt, Wrel2, brel2, Wroot2,
                                      W3, b3, nullptr, h3b, N);

  k_pool<<<B, 256, 0, stream>>>(h3b, batch, out, N, B);
}

// Round 16
// 290.458 us; speedup vs baseline: 1.2349x; 1.2349x over previous
//
#include <hip/hip_runtime.h>
#include <hip/hip_bf16.h>
#include <math.h>

// ---------------------------------------------------------------------------
// torso_left_right_actor: x@W0+b0 -> GraphConv -> tanh -> GraphConv -> tanh
//   -> @W3+b3 -> tanh -> global_mean_pool -> NormalParamExtractor
// R16 = R13 resubmit x3 (broker/container infra failures, no measurement):
//     un-fused gather (max TLP; 16 lanes x 4 rows per uint2 load = 512B/instr,
//     8 rows in flight, shfl_xor reduce). h3 fused into conv2 epilogue
//     (compute-into-compute): h2 never leaves LDS.
//     Frag layouts (HW-verified R10): A row=lane&15,k=8*(lane>>4)+i;
//     B col=lane&15 same k; C/D col=lane&15,row=(lane>>4)*4+reg.
// ---------------------------------------------------------------------------

#define CAP 64
#define FILL_PARTS 8
#define FILL_BPP 1024
typedef __hip_bfloat16 bf16;
typedef __attribute__((ext_vector_type(8))) short bf16x8;
typedef __attribute__((ext_vector_type(4))) float f32x4;

__device__ inline float bflo(unsigned u) { return __uint_as_float(u << 16); }
__device__ inline float bfhi(unsigned u) { return __uint_as_float(u & 0xFFFF0000u); }

// h = bf16(x @ W0 + b0)   (x: [N,11], W0: [11,64])
__global__ __launch_bounds__(256) void k_in(const float* __restrict__ x,
    const float* __restrict__ W0, const float* __restrict__ b0,
    bf16* __restrict__ h, int N) {
  __shared__ float w[11 * 64];
  __shared__ float xl[4][12];
  int tid = threadIdx.x;
  for (int i = tid; i < 11 * 64; i += 256) w[i] = W0[i];
  int row0 = blockIdx.x * 4;
  if (tid < 44) {
    int r = tid / 11, k = tid % 11;
    int g = row0 + r;
    xl[r][k] = (g < N) ? x[(size_t)g * 11 + k] : 0.f;
  }
  __syncthreads();
  int c = tid & 63, r = tid >> 6;
  int g = row0 + r;
  float acc = b0[c];
#pragma unroll
  for (int k = 0; k < 11; ++k) acc += xl[r][k] * w[k * 64 + c];
  if (g < N) h[(size_t)g * 64 + c] = __float2bfloat16(acc);
}

// CSR build, dst-range binned (8 partitions -> XCD-L2-local RMW).
// cnt must be pre-zeroed.
__global__ __launch_bounds__(256) void k_fill(const int* __restrict__ ei,
    int* __restrict__ cnt, int* __restrict__ csr, int E, int N) {
  int p  = blockIdx.x & 7;
  int sb = blockIdx.x >> 3;
  int nb = gridDim.x >> 3;
  int part = (N + 7) >> 3;
  int lo = p * part, hi = min(N, lo + part);
  const int* src = ei;
  const int* dst = ei + E;
  int E4 = E >> 2;
  const int4* d4 = (const int4*)dst;
  for (int i = sb * 256 + threadIdx.x; i < E4; i += nb * 256) {
    int4 dv = d4[i];
#pragma unroll
    for (int k = 0; k < 4; ++k) {
      int d = (&dv.x)[k];
      if (d >= lo && d < hi) {
        int s = src[i * 4 + k];
        int pos = atomicAdd(&cnt[d], 1);
        if (pos < CAP) csr[(size_t)d * CAP + pos] = s;
      }
    }
  }
  if (sb == 0 && threadIdx.x < (E & 3)) {   // tail edges
    int e = (E4 << 2) + threadIdx.x;
    int d = dst[e];
    if (d >= lo && d < hi) {
      int s = src[e];
      int pos = atomicAdd(&cnt[d], 1);
      if (pos < CAP) csr[(size_t)d * CAP + pos] = s;
    }
  }
}

// agg[n][:] = bf16( sum_{j in N(n)} h[j][:] ). One wave per node.
// lane = (rg:2)(fg:4): rg = row-in-flight group, fg = feature group (4 feats).
// Per load instruction: 4 rows x 16 lanes x 8B = 512B useful.
__global__ __launch_bounds__(256) void k_gather(const bf16* __restrict__ hin,
    const int* __restrict__ csr, const int* __restrict__ cnt,
    bf16* __restrict__ agg, int N) {
  int wv = __builtin_amdgcn_readfirstlane(threadIdx.x >> 6);
  int node = blockIdx.x * 4 + wv;
  if (node >= N) return;
  int lane = threadIdx.x & 63;
  int deg = min(cnt[node], CAP);              // wave-uniform broadcast
  int myidx = csr[(size_t)node * CAP + lane]; // coalesced 256B row
  int fg = lane & 15, rg = lane >> 4;
  float s0 = 0.f, s1 = 0.f, s2 = 0.f, s3 = 0.f;
  for (int j = 0; j < deg; j += 8) {
    int l0 = j + rg, l1 = j + 4 + rg;
    int i0 = __shfl(myidx, min(l0, deg - 1));
    int i1 = __shfl(myidx, min(l1, deg - 1));
    uint2 u0 = *(const uint2*)(hin + (size_t)i0 * 64 + fg * 4);
    uint2 u1 = *(const uint2*)(hin + (size_t)i1 * 64 + fg * 4);
    if (l0 < deg) {
      s0 += bflo(u0.x); s1 += bfhi(u0.x);
      s2 += bflo(u0.y); s3 += bfhi(u0.y);
    }
    if (l1 < deg) {
      s0 += bflo(u1.x); s1 += bfhi(u1.x);
      s2 += bflo(u1.y); s3 += bfhi(u1.y);
    }
  }
  // reduce across the 4 rg groups (lanes fg, fg+16, fg+32, fg+48)
  s0 += __shfl_xor(s0, 16); s0 += __shfl_xor(s0, 32);
  s1 += __shfl_xor(s1, 16); s1 += __shfl_xor(s1, 32);
  s2 += __shfl_xor(s2, 16); s2 += __shfl_xor(s2, 32);
  s3 += __shfl_xor(s3, 16); s3 += __shfl_xor(s3, 32);
  if (rg == 0) {
    bf16 o[4] = {__float2bfloat16(s0), __float2bfloat16(s1),
                 __float2bfloat16(s2), __float2bfloat16(s3)};
    *(uint2*)(agg + (size_t)node * 64 + fg * 4) = *(uint2*)o;
  }
}

// out = bf16(tanh(A @ Wrel + brel + H @ Wroot)), all [N,64] bf16.
// One 64-row supertile per block, 16 rows per wave, MFMA 16x16x32.
// DO_H3=1: instead of storing h2, keep it in LDS and emit
//          h3out = tanh(h2 @ W3 + b3) [N,16].
// Dynamic LDS: [0,32KB) = wlds f32[2][64][64]; [32KB,..) = tile bf16[4][16][72].
template <int DO_H3>
__global__ __launch_bounds__(256) void k_convm(const bf16* A, const bf16* H,
    const float* __restrict__ Wrel, const float* __restrict__ brel,
    const float* __restrict__ Wroot, const float* __restrict__ W3,
    const float* __restrict__ b3, bf16* hout, float* __restrict__ h3out,
    int N) {
  extern __shared__ char smem[];
  float* wlds = (float*)smem;                 // [2][64*64]
  bf16* tile = (bf16*)(smem + 32768);         // [4][16][72] (DO_H3 only)
  int tid = threadIdx.x;
  for (int i = tid * 4; i < 64 * 64; i += 1024) {
    *(float4*)(wlds + i) = *(const float4*)(Wrel + i);
    *(float4*)(wlds + 4096 + i) = *(const float4*)(Wroot + i);
  }
  __syncthreads();
  int lane = tid & 63;
  int wv = __builtin_amdgcn_readfirstlane(tid >> 6);
  int lr = lane & 15;
  int lk = lane >> 4;

  // B-frags: lane holds W[k = lk*8+i+ks*32][col = lr+cb*16]
  bf16x8 wr[4][2], wo[4][2];
#pragma unroll
  for (int cb = 0; cb < 4; ++cb) {
#pragma unroll
    for (int ks = 0; ks < 2; ++ks) {
      bf16* pr = (bf16*)&wr[cb][ks];
      bf16* po = (bf16*)&wo[cb][ks];
#pragma unroll
      for (int i = 0; i < 8; ++i) {
        int k = lk * 8 + i + ks * 32;
        int col = lr + cb * 16;
        pr[i] = __float2bfloat16(wlds[k * 64 + col]);
        po[i] = __float2bfloat16(wlds[4096 + k * 64 + col]);
      }
    }
  }
  int rb = blockIdx.x * 64 + wv * 16;
  if (rb >= N) return;
  int arow = min(rb + lr, N - 1);
  const bf16x8* Ap = (const bf16x8*)(A + (size_t)arow * 64 + lk * 8);
  const bf16x8* Hp = (const bf16x8*)(H + (size_t)arow * 64 + lk * 8);
  bf16x8 a0 = Ap[0], a1 = Ap[4];
  bf16x8 h0 = Hp[0], h1 = Hp[4];

  f32x4 acc[4];
#pragma unroll
  for (int cb = 0; cb < 4; ++cb) {
    float bb = brel[cb * 16 + lr];
    f32x4 c0 = {bb, bb, bb, bb};
    c0 = __builtin_amdgcn_mfma_f32_16x16x32_bf16(a0, wr[cb][0], c0, 0, 0, 0);
    c0 = __builtin_amdgcn_mfma_f32_16x16x32_bf16(a1, wr[cb][1], c0, 0, 0, 0);
    c0 = __builtin_amdgcn_mfma_f32_16x16x32_bf16(h0, wo[cb][0], c0, 0, 0, 0);
    c0 = __builtin_amdgcn_mfma_f32_16x16x32_bf16(h1, wo[cb][1], c0, 0, 0, 0);
    acc[cb] = c0;
  }
  if (!DO_H3) {
#pragma unroll
    for (int cb = 0; cb < 4; ++cb)
#pragma unroll
      for (int r = 0; r < 4; ++r) {
        int row = rb + lk * 4 + r;
        if (row < N)
          hout[(size_t)row * 64 + cb * 16 + lr] = __float2bfloat16(tanhf(acc[cb][r]));
      }
  } else {
    bf16* mytile = tile + wv * 16 * 72;
#pragma unroll
    for (int cb = 0; cb < 4; ++cb)
#pragma unroll
      for (int r = 0; r < 4; ++r)
        mytile[(lk * 4 + r) * 72 + cb * 16 + lr] = __float2bfloat16(tanhf(acc[cb][r]));
    // same-wave LDS write->read; tile is private to this wave
    bf16x8 p0 = *(const bf16x8*)&mytile[lr * 72 + lk * 8];
    bf16x8 p1 = *(const bf16x8*)&mytile[lr * 72 + lk * 8 + 32];
    bf16x8 q0, q1;
    bf16* q0p = (bf16*)&q0;
    bf16* q1p = (bf16*)&q1;
#pragma unroll
    for (int i = 0; i < 8; ++i) {  // W3 [64,16], 4KB L2-hot
      q0p[i] = __float2bfloat16(W3[(lk * 8 + i) * 16 + lr]);
      q1p[i] = __float2bfloat16(W3[(lk * 8 + i + 32) * 16 + lr]);
    }
    float b3v = b3[lr];
    f32x4 c3 = {b3v, b3v, b3v, b3v};
    c3 = __builtin_amdgcn_mfma_f32_16x16x32_bf16(p0, q0, c3, 0, 0, 0);
    c3 = __builtin_amdgcn_mfma_f32_16x16x32_bf16(p1, q1, c3, 0, 0, 0);
#pragma unroll
    for (int r = 0; r < 4; ++r) {
      int row = rb + lk * 4 + r;
      if (row < N) h3out[(size_t)row * 16 + lr] = tanhf(c3[r]);
    }
  }
}

// Per-graph mean pool + NormalParamExtractor. batch is sorted.
__global__ __launch_bounds__(256) void k_pool(const float* __restrict__ h3,
    const int* __restrict__ batch, float* __restrict__ out, int N, int B) {
  __shared__ int srange[2];
  __shared__ float red[256];
  int b = blockIdx.x;
  int tid = threadIdx.x;
  if (tid < 2) {
    int target = b + tid;
    int lo = 0, hi = N;
    while (lo < hi) {
      int mid = (lo + hi) >> 1;
      if (batch[mid] < target) lo = mid + 1; else hi = mid;
    }
    srange[tid] = lo;
  }
  __syncthreads();
  int s = srange[0], e = srange[1];
  int f = tid & 15, g = tid >> 4;
  float acc = 0.f;
  for (int n = s + g; n < e; n += 16) acc += h3[(size_t)n * 16 + f];
  red[tid] = acc;
  __syncthreads();
  for (int stride = 128; stride >= 16; stride >>= 1) {
    if (tid < stride) red[tid] += red[tid + stride];
    __syncthreads();
  }
  if (tid < 16) {
    float cnt = (float)(e - s);
    float pooled = red[tid] / fmaxf(cnt, 1.0f);
    if (tid < 8) {
      out[(size_t)b * 8 + tid] = pooled;
    } else {
      float xx = pooled + 0.54132485461292f;  // log(expm1(1.0))
      float sp = (xx > 20.f) ? xx : log1pf(expf(xx));
      out[(size_t)B * 8 + (size_t)b * 8 + (tid - 8)] = fmaxf(sp, 1e-4f);
    }
  }
}

extern "C" void kernel_launch(void* const* d_in, const int* in_sizes, int n_in,
                              void* d_out, int out_size, void* d_ws, size_t ws_size,
                              hipStream_t stream) {
  const float* x      = (const float*)d_in[0];
  const int*   ei     = (const int*)d_in[1];
  const int*   batch  = (const int*)d_in[2];
  const float* W0     = (const float*)d_in[3];
  const float* b0     = (const float*)d_in[4];
  const float* Wrel1  = (const float*)d_in[5];
  const float* brel1  = (const float*)d_in[6];
  const float* Wroot1 = (const float*)d_in[7];
  const float* Wrel2  = (const float*)d_in[8];
  const float* brel2  = (const float*)d_in[9];
  const float* Wroot2 = (const float*)d_in[10];
  const float* W3     = (const float*)d_in[11];
  const float* b3     = (const float*)d_in[12];
  float* out = (float*)d_out;

  int N = in_sizes[0] / 11;
  int E = in_sizes[1] / 2;
  int B = out_size / 16;

  bf16*  hb   = (bf16*)d_ws;                      // [N,64] bf16 (h0 -> h1)
  bf16*  aggb = hb + (size_t)N * 64;              // [N,64] bf16
  float* h3b  = (float*)(aggb + (size_t)N * 64);  // [N,16] f32
  int*   cnt  = (int*)(h3b + (size_t)N * 16);     // [N]
  int*   csr  = cnt + N;                          // [N,CAP]

  int nst = (N + 63) / 64;

  hipMemsetAsync(cnt, 0, (size_t)N * sizeof(int), stream);
  k_in<<<(N + 3) / 4, 256, 0, stream>>>(x, W0, b0, hb, N);
  k_fill<<<FILL_PARTS * FILL_BPP, 256, 0, stream>>>(ei, cnt, csr, E, N);

  // layer 1: gather(hb) -> aggb; conv1 in-place over hb
  k_gather<<<(N + 3) / 4, 256, 0, stream>>>(hb, csr, cnt, aggb, N);
  k_convm<0><<<nst, 256, 32768, stream>>>(aggb, hb, Wrel1, brel1, Wroot1,
                                          nullptr, nullptr, hb, nullptr, N);
  // layer 2: gather(hb=h1) -> aggb; conv2 + fused h3 -> h3b (h2 stays in LDS)
  k_gather<<<(N + 3) / 4, 256, 0, stream>>>(hb, csr, cnt, aggb, N);
  k_convm<1><<<nst, 256, 32768 + 4 * 16 * 72 * 2, stream>>>(
      aggb, hb, Wrel2, brel2, Wroot2, W3, b3, nullptr, h3b, N);

  k_pool<<<B, 256, 0, stream>>>(h3b, batch, out, N, B);
}

// Round 18
// 282.943 us; speedup vs baseline: 1.2677x; 1.0266x over previous
//
#include <hip/hip_runtime.h>
#include <hip/hip_bf16.h>
#include <math.h>

// ---------------------------------------------------------------------------
// torso_left_right_actor: x@W0+b0 -> GraphConv -> tanh -> GraphConv -> tanh
//   -> @W3+b3 -> tanh -> global_mean_pool -> NormalParamExtractor
// R18 = R17 resubmit (broker timeout, no measurement):
//     fused register-gather-conv. Each wave gathers 16 nodes IN PARALLEL
//     straight into MFMA A-frag layout (lane l: features 8*(l>>4)(+32) of
//     node l&15), f32 accum in registers, zero LDS (layer1). CSR slots held
//     in 16 regs/lane, distributed via shfl (compile-time reg idx).
//     agg tensor eliminated. h3 fused in layer2 (9KB LDS tile only).
//     Layer1 writes a separate buffer (fused blocks read arbitrary rows).
//     Frag layouts (HW-verified R10): A row=lane&15,k=8*(lane>>4)+i;
//     B col=lane&15 same k; C/D col=lane&15,row=(lane>>4)*4+reg.
// ---------------------------------------------------------------------------

#define CAP 64
#define FILL_PARTS 8
#define FILL_BPP 1024
typedef __hip_bfloat16 bf16;
typedef __attribute__((ext_vector_type(8))) short bf16x8;
typedef __attribute__((ext_vector_type(4))) float f32x4;

__device__ inline float bflo(unsigned u) { return __uint_as_float(u << 16); }
__device__ inline float bfhi(unsigned u) { return __uint_as_float(u & 0xFFFF0000u); }

// h = bf16(x @ W0 + b0)   (x: [N,11], W0: [11,64])
__global__ __launch_bounds__(256) void k_in(const float* __restrict__ x,
    const float* __restrict__ W0, const float* __restrict__ b0,
    bf16* __restrict__ h, int N) {
  __shared__ float w[11 * 64];
  __shared__ float xl[4][12];
  int tid = threadIdx.x;
  for (int i = tid; i < 11 * 64; i += 256) w[i] = W0[i];
  int row0 = blockIdx.x * 4;
  if (tid < 44) {
    int r = tid / 11, k = tid % 11;
    int g = row0 + r;
    xl[r][k] = (g < N) ? x[(size_t)g * 11 + k] : 0.f;
  }
  __syncthreads();
  int c = tid & 63, r = tid >> 6;
  int g = row0 + r;
  float acc = b0[c];
#pragma unroll
  for (int k = 0; k < 11; ++k) acc += xl[r][k] * w[k * 64 + c];
  if (g < N) h[(size_t)g * 64 + c] = __float2bfloat16(acc);
}

// CSR build, dst-range binned (8 partitions -> XCD-L2-local RMW).
// cnt must be pre-zeroed.
__global__ __launch_bounds__(256) void k_fill(const int* __restrict__ ei,
    int* __restrict__ cnt, int* __restrict__ csr, int E, int N) {
  int p  = blockIdx.x & 7;
  int sb = blockIdx.x >> 3;
  int nb = gridDim.x >> 3;
  int part = (N + 7) >> 3;
  int lo = p * part, hi = min(N, lo + part);
  const int* src = ei;
  const int* dst = ei + E;
  int E4 = E >> 2;
  const int4* d4 = (const int4*)dst;
  for (int i = sb * 256 + threadIdx.x; i < E4; i += nb * 256) {
    int4 dv = d4[i];
#pragma unroll
    for (int k = 0; k < 4; ++k) {
      int d = (&dv.x)[k];
      if (d >= lo && d < hi) {
        int s = src[i * 4 + k];
        int pos = atomicAdd(&cnt[d], 1);
        if (pos < CAP) csr[(size_t)d * CAP + pos] = s;
      }
    }
  }
  if (sb == 0 && threadIdx.x < (E & 3)) {   // tail edges
    int e = (E4 << 2) + threadIdx.x;
    int d = dst[e];
    if (d >= lo && d < hi) {
      int s = src[e];
      int pos = atomicAdd(&cnt[d], 1);
      if (pos < CAP) csr[(size_t)d * CAP + pos] = s;
    }
  }
}

// Fused gather+conv: out = bf16(tanh(agg @ Wrel + brel + hin @ Wroot)).
// Wave handles 16 nodes; gather accumulates directly into A-frag layout:
// lane l sums features [8*(l>>4), +8) and [32+8*(l>>4), +8) of node
// rb + wv*16 + (l&15). DO_H3=1: h2 -> LDS tile -> h3 = tanh(h2@W3+b3).
// hout MUST NOT alias hin (blocks read arbitrary rows of hin).
template <int DO_H3>
__global__ __launch_bounds__(256) void k_gconv(
    const bf16* __restrict__ hin, const int* __restrict__ csr,
    const int* __restrict__ cnt, const float* __restrict__ Wrel,
    const float* __restrict__ brel, const float* __restrict__ Wroot,
    const float* __restrict__ W3, const float* __restrict__ b3,
    bf16* __restrict__ hout, float* __restrict__ h3out, int N) {
  extern __shared__ char smem[];  // DO_H3 only: bf16 tile[4][16][72]
  int tid = threadIdx.x;
  int lane = tid & 63;
  int wv = __builtin_amdgcn_readfirstlane(tid >> 6);
  int lr = lane & 15, lk = lane >> 4;
  int rb = blockIdx.x * 64 + wv * 16;
  int node = rb + lr;
  int nodec = min(node, N - 1);

  // my 16 CSR slots: slots [16*lk, +16) of node nodec
  int s[16];
  {
    const int4* p = (const int4*)(csr + (size_t)nodec * CAP + lk * 16);
    int4 v0 = p[0], v1 = p[1], v2 = p[2], v3 = p[3];
    s[0] = v0.x; s[1] = v0.y; s[2] = v0.z;  s[3] = v0.w;
    s[4] = v1.x; s[5] = v1.y; s[6] = v1.z;  s[7] = v1.w;
    s[8] = v2.x; s[9] = v2.y; s[10] = v2.z; s[11] = v2.w;
    s[12] = v3.x; s[13] = v3.y; s[14] = v3.z; s[15] = v3.w;
  }
  int deg = (node < N) ? min(cnt[nodec], CAP) : 0;  // same for 4 replicas

  // gather: f32 accum of my 8+8 features over my node's edges
  float aLo[8] = {0, 0, 0, 0, 0, 0, 0, 0};
  float aHi[8] = {0, 0, 0, 0, 0, 0, 0, 0};
  for (int jb = 0; jb < 4; ++jb) {
#pragma unroll
    for (int ji = 0; ji < 16; ++ji) {
      int j = (jb << 4) + ji;
      int src = __shfl(s[ji], lr + (jb << 4));
      if (j < deg) {
        const bf16* rowp = hin + (size_t)src * 64 + lk * 8;
        uint4 lo = *(const uint4*)(rowp);
        uint4 hi = *(const uint4*)(rowp + 32);
        aLo[0] += bflo(lo.x); aLo[1] += bfhi(lo.x);
        aLo[2] += bflo(lo.y); aLo[3] += bfhi(lo.y);
        aLo[4] += bflo(lo.z); aLo[5] += bfhi(lo.z);
        aLo[6] += bflo(lo.w); aLo[7] += bfhi(lo.w);
        aHi[0] += bflo(hi.x); aHi[1] += bfhi(hi.x);
        aHi[2] += bflo(hi.y); aHi[3] += bfhi(hi.y);
        aHi[4] += bflo(hi.z); aHi[5] += bfhi(hi.z);
        aHi[6] += bflo(hi.w); aHi[7] += bfhi(hi.w);
      }
    }
    if (__all(deg <= ((jb + 1) << 4))) break;  // deg<=32 w.h.p. -> 2 rounds
  }

  // pack A-frags (agg) and load H-frags (root)
  bf16x8 a0, a1;
#pragma unroll
  for (int i = 0; i < 8; ++i) {
    ((bf16*)&a0)[i] = __float2bfloat16(aLo[i]);
    ((bf16*)&a1)[i] = __float2bfloat16(aHi[i]);
  }
  const bf16* hrow = hin + (size_t)nodec * 64 + lk * 8;
  bf16x8 h0 = *(const bf16x8*)(hrow);
  bf16x8 h1 = *(const bf16x8*)(hrow + 32);

  // B-frags straight from global f32 (L2-hot 32KB; 64B-coalesced per instr)
  f32x4 acc[4];
#pragma unroll
  for (int cb = 0; cb < 4; ++cb) {
    bf16x8 br0, br1, bo0, bo1;
#pragma unroll
    for (int i = 0; i < 8; ++i) {
      int k0 = lk * 8 + i;
      int col = cb * 16 + lr;
      ((bf16*)&br0)[i] = __float2bfloat16(Wrel[k0 * 64 + col]);
      ((bf16*)&br1)[i] = __float2bfloat16(Wrel[(k0 + 32) * 64 + col]);
      ((bf16*)&bo0)[i] = __float2bfloat16(Wroot[k0 * 64 + col]);
      ((bf16*)&bo1)[i] = __float2bfloat16(Wroot[(k0 + 32) * 64 + col]);
    }
    float bb = brel[cb * 16 + lr];
    f32x4 c0 = {bb, bb, bb, bb};
    c0 = __builtin_amdgcn_mfma_f32_16x16x32_bf16(a0, br0, c0, 0, 0, 0);
    c0 = __builtin_amdgcn_mfma_f32_16x16x32_bf16(a1, br1, c0, 0, 0, 0);
    c0 = __builtin_amdgcn_mfma_f32_16x16x32_bf16(h0, bo0, c0, 0, 0, 0);
    c0 = __builtin_amdgcn_mfma_f32_16x16x32_bf16(h1, bo1, c0, 0, 0, 0);
    acc[cb] = c0;
  }

  if (!DO_H3) {
    // D: col = cb*16+lr, row = rb + lk*4 + r
#pragma unroll
    for (int cb = 0; cb < 4; ++cb)
#pragma unroll
      for (int r = 0; r < 4; ++r) {
        int row = rb + lk * 4 + r;
        if (row < N)
          hout[(size_t)row * 64 + cb * 16 + lr] = __float2bfloat16(tanhf(acc[cb][r]));
      }
  } else {
    bf16* mytile = (bf16*)smem + wv * 16 * 72;
#pragma unroll
    for (int cb = 0; cb < 4; ++cb)
#pragma unroll
      for (int r = 0; r < 4; ++r)
        mytile[(lk * 4 + r) * 72 + cb * 16 + lr] = __float2bfloat16(tanhf(acc[cb][r]));
    // same-wave LDS write->read (tile private to wave)
    bf16x8 p0 = *(const bf16x8*)&mytile[lr * 72 + lk * 8];
    bf16x8 p1 = *(const bf16x8*)&mytile[lr * 72 + lk * 8 + 32];
    bf16x8 q0, q1;
#pragma unroll
    for (int i = 0; i < 8; ++i) {  // W3 [64,16], 4KB L2-hot
      ((bf16*)&q0)[i] = __float2bfloat16(W3[(lk * 8 + i) * 16 + lr]);
      ((bf16*)&q1)[i] = __float2bfloat16(W3[(lk * 8 + i + 32) * 16 + lr]);
    }
    float b3v = b3[lr];
    f32x4 c3 = {b3v, b3v, b3v, b3v};
    c3 = __builtin_amdgcn_mfma_f32_16x16x32_bf16(p0, q0, c3, 0, 0, 0);
    c3 = __builtin_amdgcn_mfma_f32_16x16x32_bf16(p1, q1, c3, 0, 0, 0);
#pragma unroll
    for (int r = 0; r < 4; ++r) {
      int row = rb + lk * 4 + r;
      if (row < N) h3out[(size_t)row * 16 + lr] = tanhf(c3[r]);
    }
  }
}

// Per-graph mean pool + NormalParamExtractor. batch is sorted.
__global__ __launch_bounds__(256) void k_pool(const float* __restrict__ h3,
    const int* __restrict__ batch, float* __restrict__ out, int N, int B) {
  __shared__ int srange[2];
  __shared__ float red[256];
  int b = blockIdx.x;
  int tid = threadIdx.x;
  if (tid < 2) {
    int target = b + tid;
    int lo = 0, hi = N;
    while (lo < hi) {
      int mid = (lo + hi) >> 1;
      if (batch[mid] < target) lo = mid + 1; else hi = mid;
    }
    srange[tid] = lo;
  }
  __syncthreads();
  int s = srange[0], e = srange[1];
  int f = tid & 15, g = tid >> 4;
  float acc = 0.f;
  for (int n = s + g; n < e; n += 16) acc += h3[(size_t)n * 16 + f];
  red[tid] = acc;
  __syncthreads();
  for (int stride = 128; stride >= 16; stride >>= 1) {
    if (tid < stride) red[tid] += red[tid + stride];
    __syncthreads();
  }
  if (tid < 16) {
    float cnt = (float)(e - s);
    float pooled = red[tid] / fmaxf(cnt, 1.0f);
    if (tid < 8) {
      out[(size_t)b * 8 + tid] = pooled;
    } else {
      float xx = pooled + 0.54132485461292f;  // log(expm1(1.0))
      float sp = (xx > 20.f) ? xx : log1pf(expf(xx));
      out[(size_t)B * 8 + (size_t)b * 8 + (tid - 8)] = fmaxf(sp, 1e-4f);
    }
  }
}

extern "C" void kernel_launch(void* const* d_in, const int* in_sizes, int n_in,
                              void* d_out, int out_size, void* d_ws, size_t ws_size,
                              hipStream_t stream) {
  const float* x      = (const float*)d_in[0];
  const int*   ei     = (const int*)d_in[1];
  const int*   batch  = (const int*)d_in[2];
  const float* W0     = (const float*)d_in[3];
  const float* b0     = (const float*)d_in[4];
  const float* Wrel1  = (const float*)d_in[5];
  const float* brel1  = (const float*)d_in[6];
  const float* Wroot1 = (const float*)d_in[7];
  const float* Wrel2  = (const float*)d_in[8];
  const float* brel2  = (const float*)d_in[9];
  const float* Wroot2 = (const float*)d_in[10];
  const float* W3     = (const float*)d_in[11];
  const float* b3     = (const float*)d_in[12];
  float* out = (float*)d_out;

  int N = in_sizes[0] / 11;
  int E = in_sizes[1] / 2;
  int B = out_size / 16;

  bf16*  hb   = (bf16*)d_ws;                      // [N,64] bf16 (h0)
  bf16*  h1b  = hb + (size_t)N * 64;              // [N,64] bf16 (h1)
  float* h3b  = (float*)(h1b + (size_t)N * 64);   // [N,16] f32
  int*   cnt  = (int*)(h3b + (size_t)N * 16);     // [N]
  int*   csr  = cnt + N;                          // [N,CAP]

  int nst = (N + 63) / 64;

  hipMemsetAsync(cnt, 0, (size_t)N * sizeof(int), stream);
  k_in<<<(N + 3) / 4, 256, 0, stream>>>(x, W0, b0, hb, N);
  k_fill<<<FILL_PARTS * FILL_BPP, 256, 0, stream>>>(ei, cnt, csr, E, N);

  // layer 1: fused gather+conv, hb -> h1b (no aliasing!)
  k_gconv<0><<<nst, 256, 0, stream>>>(hb, csr, cnt, Wrel1, brel1, Wroot1,
                                      nullptr, nullptr, h1b, nullptr, N);
  // layer 2: fused gather+conv+h3, h1b -> h3b (h2 stays in LDS)
  k_gconv<1><<<nst, 256, 4 * 16 * 72 * 2, stream>>>(
      h1b, csr, cnt, Wrel2, brel2, Wroot2, W3, b3, nullptr, h3b, N);

  k_pool<<<B, 256, 0, stream>>>(h3b, batch, out, N, B);
}